// Round 12
// baseline (97.756 us; speedup 1.0000x reference)
//
#include <hip/hip_runtime.h>
#include <hip/hip_bf16.h>

#define N_NODES 16000
#define IN_F 128
#define HID 64
#define BATCH 32
#define NPAIR 128
#define DRES 100
#define NCLS 10

// workspace layout (float offsets)
#define NF_OFF     0
#define WT1_OFF    16000                 // [2 ic][25 tap][16 oc] fp32 (800)
#define WT2B_OFF   16800                 // [200 kp][32 oc] packed bf16 pairs (6400 uint)
#define INV_OFF    23200                 // [64] per-(b,c) 1/max
#define CNT_OFF    23264                 // [64] finisher counters (zeroed)
#define IMGSP_OFF  23328                 // [32][2][104][104] padded
#define POOL1P_OFF 715552                // [32][16][54][56] padded
#define POOL2_OFF  2263840               // [32][32][25][25]
#define ZERO_N4    560144                // (64 cnt + imgs + pool1p)/4 float4s, base CNT_OFF

#define NFILT_BLK  125                   // filt blocks (4 waves x 32 nodes = 128 nodes)
#define NZBLK      548                   // zero blocks (1024 float4 each)

// float2 patch element access (compile-time index under full unroll)
#define PV(P, r, c) (((c) & 1) ? P[(r)*3 + ((c)>>1)].y : P[(r)*3 + ((c)>>1)].x)

typedef short short8 __attribute__((ext_vector_type(8)));
typedef float f32x16 __attribute__((ext_vector_type(16)));

static __device__ __forceinline__ unsigned short f2b(float f) {
    __hip_bfloat16 h = __float2bfloat16(f);
    return *reinterpret_cast<unsigned short*>(&h);
}
static __device__ __forceinline__ unsigned int pk2(float a, float b) {
    return (unsigned int)f2b(a) | ((unsigned int)f2b(b) << 16);
}

// element offset of k=(ic,kh,kw) within inb[16][6][56] (tile row-base 0)
#define COFF(k) (((k)/25)*336 + (((k)%25)/5)*56 + ((k)%25)%5)

// ---------------- Kernel IF: filt MLP (MFMA) + weight prep + zero ----------------
// bx<125: filtration (wave = 32 nodes, B-fragments loaded direct from w1);
// bx==125: wT1 prep; bx==126: wT2b prep; bx>=127: zero cnt+imgs+pool1p.
__global__ __launch_bounds__(256) void k_initfilt(
    const float* __restrict__ x, const float* __restrict__ w1,
    const float* __restrict__ b1, const float* __restrict__ w2,
    const float* __restrict__ b2, float* __restrict__ nf, float* __restrict__ out_nf,
    const float* __restrict__ c1w, const float* __restrict__ c2w,
    float* __restrict__ wT1, unsigned int* __restrict__ wT2b,
    float* __restrict__ zbase)
{
    int bx = blockIdx.x, t = threadIdx.x;
    if (bx < NFILT_BLK) {
        int wave = t >> 6, lane = t & 63;
        int n0 = (bx * 4 + wave) * 32;
        int hh = lane >> 5, sm = lane & 31;
        const float* xr = x + (size_t)(n0 + sm) * IN_F + hh * 8;
        const float* wbase = w1 + hh * 512 + sm;   // w1[(8hh)*64 + sm]

        f32x16 acc0 = {0.f,0.f,0.f,0.f,0.f,0.f,0.f,0.f,0.f,0.f,0.f,0.f,0.f,0.f,0.f,0.f};
        f32x16 acc1 = {0.f,0.f,0.f,0.f,0.f,0.f,0.f,0.f,0.f,0.f,0.f,0.f,0.f,0.f,0.f,0.f};

        #pragma unroll
        for (int s = 0; s < 8; ++s) {
            float4 v0 = *(const float4*)(xr + s * 16);
            float4 v1 = *(const float4*)(xr + s * 16 + 4);
            union { short8 v; unsigned int u[4]; } a;
            a.u[0] = pk2(v0.x, v0.y);
            a.u[1] = pk2(v0.z, v0.w);
            a.u[2] = pk2(v1.x, v1.y);
            a.u[3] = pk2(v1.z, v1.w);
            union { short8 v; unsigned int u[4]; } b0f, b1f;
            #pragma unroll
            for (int r = 0; r < 4; ++r) {
                // k0 = 16s + 8hh + 2r, hid = nt*32 + sm; w1[k][hid] row-major [128][64]
                float wa0 = wbase[s * 1024 + r * 128];        // nt=0, k0
                float wb0 = wbase[s * 1024 + r * 128 + 64];   // nt=0, k0+1
                float wa1 = wbase[s * 1024 + r * 128 + 32];   // nt=1, k0
                float wb1v = wbase[s * 1024 + r * 128 + 96];  // nt=1, k0+1
                b0f.u[r] = pk2(wa0, wb0);
                b1f.u[r] = pk2(wa1, wb1v);
            }
            acc0 = __builtin_amdgcn_mfma_f32_32x32x16_bf16(a.v, b0f.v, acc0, 0, 0, 0);
            acc1 = __builtin_amdgcn_mfma_f32_32x32x16_bf16(a.v, b1f.v, acc1, 0, 0, 0);
        }

        int h0 = sm, h1 = 32 + sm;
        float b10 = b1[h0], b11 = b1[h1], w20 = w2[h0], w21 = w2[h1];
        float q[16];
        #pragma unroll
        for (int r = 0; r < 16; ++r)
            q[r] = fmaxf(acc0[r] + b10, 0.f) * w20 + fmaxf(acc1[r] + b11, 0.f) * w21;
        #pragma unroll
        for (int off = 1; off < 32; off <<= 1) {
            #pragma unroll
            for (int r = 0; r < 16; ++r)
                q[r] += __shfl_xor(q[r], off, 64);
        }
        if (sm == 0) {
            float b2v = b2[0];
            #pragma unroll
            for (int r = 0; r < 16; ++r) {
                int m = (r & 3) + 8 * (r >> 2) + 4 * hh;
                float f = 1.f / (1.f + expf(-(q[r] + b2v)));
                nf[n0 + m] = f;
                out_nf[n0 + m] = f;
            }
        }
        return;
    }
    if (bx == NFILT_BLK) {
        for (int i = t; i < 800; i += 256) {
            int ic = i / 400, tap = (i / 16) % 25, oc = i % 16;
            wT1[i] = c1w[(oc * 2 + ic) * 25 + tap];
        }
        return;
    }
    if (bx == NFILT_BLK + 1) {
        for (int i = t; i < 6400; i += 256) {
            int kp = i >> 5, oc = i & 31;
            int k0 = 2 * kp, k1 = k0 + 1;
            float f0 = c2w[(oc * 16 + k0 / 25) * 25 + k0 % 25];
            float f1 = c2w[(oc * 16 + k1 / 25) * 25 + k1 % 25];
            wT2b[i] = pk2(f0, f1);
        }
        return;
    }
    int zi = (bx - (NFILT_BLK + 2)) * 1024 + t;
    float4 z = make_float4(0.f, 0.f, 0.f, 0.f);
    #pragma unroll
    for (int r = 0; r < 4; ++r) {
        int i = zi + r * 256;
        if (i < ZERO_N4) ((float4*)zbase)[i] = z;
    }
}

// ---------------- Kernel B: persistence image + last-finisher inv ----------------
// 256 blocks (img, quarter); 4th finisher of an image computes inv[img].
__global__ __launch_bounds__(256) void k_pimg(const float* __restrict__ nf,
    const int* __restrict__ pi0, const int* __restrict__ pi1,
    float* __restrict__ imgs_p, unsigned int* __restrict__ cnt,
    float* __restrict__ inv)
{
    int g = blockIdx.x;
    int img = (g & 7) * 8 + ((g >> 3) & 7);
    int q = g >> 6;
    int b = img >> 1, c = img & 1;
    const int* pi = c ? pi1 : pi0;
    __shared__ float sb[32], sp[32];
    __shared__ unsigned int sOld;
    __shared__ float wm[4];
    int t = threadIdx.x;
    if (t < 32) {
        int p = q * 32 + t;
        int i0 = pi[(b * NPAIR + p) * 2 + 0];
        int i1 = pi[(b * NPAIR + p) * 2 + 1];
        float f0 = nf[i0], f1 = nf[i1];
        sb[t] = f0;
        sp[t] = f1 - f0;
    }
    __syncthreads();
    bool act = t < 169;
    int ti = t / 13, tj = t % 13;
    if (act) {
        float ci[8], cj[8];
        #pragma unroll
        for (int r = 0; r < 8; ++r) {
            ci[r] = (float)(ti + 13 * r) * 0.01f;
            cj[r] = (float)(tj + 13 * r) * 0.01f;
        }
        float acc[8][8];
        #pragma unroll
        for (int r = 0; r < 8; ++r)
            #pragma unroll
            for (int s = 0; s < 8; ++s) acc[r][s] = 0.f;
        for (int p = 0; p < 32; ++p) {
            float bb = sb[p], pp = sp[p];
            float eb[8], ep[8];
            #pragma unroll
            for (int r = 0; r < 8; ++r) { float d = bb - ci[r]; eb[r] = __expf(-d * d); }
            #pragma unroll
            for (int s = 0; s < 8; ++s) { float d = pp - cj[s]; ep[s] = __expf(-d * d); }
            #pragma unroll
            for (int r = 0; r < 8; ++r)
                #pragma unroll
                for (int s = 0; s < 8; ++s)
                    acc[r][s] = fmaf(eb[r], ep[s], acc[r][s]);
        }
        float* dst = imgs_p + (size_t)img * 10816 + 2 * 104 + 2;
        #pragma unroll
        for (int r = 0; r < 8; ++r) {
            int i = ti + 13 * r;
            if (i < DRES) {
                #pragma unroll
                for (int s = 0; s < 8; ++s) {
                    int j = tj + 13 * s;
                    if (j < DRES) atomicAdd(&dst[i * 104 + j], acc[r][s]);
                }
            }
        }
    }
    __threadfence();
    __syncthreads();
    if (t == 0) sOld = atomicAdd(&cnt[img], 1u);
    __syncthreads();
    if (sOld == 3u) {
        __threadfence();
        volatile const float* src = imgs_p + (size_t)img * 10816;
        float m = 0.f;
        for (int k = t; k < 10816; k += 256) m = fmaxf(m, src[k]);
        #pragma unroll
        for (int off = 32; off > 0; off >>= 1)
            m = fmaxf(m, __shfl_xor(m, off, 64));
        if ((t & 63) == 0) wm[t >> 6] = m;
        __syncthreads();
        if (t == 0) {
            float bm = fmaxf(fmaxf(wm[0], wm[1]), fmaxf(wm[2], wm[3]));
            inv[img] = 1.f / bm;
        }
    }
}

// ---------------- Kernel C: conv1 + relu + maxpool2 (VALU) ----------------
__global__ __launch_bounds__(256) void k_conv1(const float* __restrict__ imgs_p,
    const float* __restrict__ wT1, const float* __restrict__ cb,
    const float* __restrict__ inv, float* __restrict__ pool1p)
{
    int g = blockIdx.x;
    int b = (g & 7) * 4 + ((g >> 3) & 3);
    int ocg = (g >> 5) & 3;
    int rg = g >> 7;
    int t = threadIdx.x;
    if (t >= 250) return;
    int ow = t % 50, oh = rg * 5 + t / 50;

    float2 PA[18], PB[18];
    {
        const float* bs = imgs_p + (size_t)(b * 2 + 0) * 10816 + (2 * oh) * 104 + 2 * ow;
        #pragma unroll
        for (int r = 0; r < 6; ++r) {
            const float* rp = bs + r * 104;
            PA[r * 3 + 0] = *(const float2*)rp;
            PA[r * 3 + 1] = *(const float2*)(rp + 2);
            PA[r * 3 + 2] = *(const float2*)(rp + 4);
        }
        const float* bs1 = bs + 10816;
        #pragma unroll
        for (int r = 0; r < 6; ++r) {
            const float* rp = bs1 + r * 104;
            PB[r * 3 + 0] = *(const float2*)rp;
            PB[r * 3 + 1] = *(const float2*)(rp + 2);
            PB[r * 3 + 2] = *(const float2*)(rp + 4);
        }
    }
    float acc0[4][2][2] = {}, acc1[4][2][2] = {};
    const float* w0 = wT1 + ocg * 4;
    const float* w1r = wT1 + 400 + ocg * 4;
    #pragma unroll
    for (int kh = 0; kh < 5; ++kh)
        #pragma unroll
        for (int kw = 0; kw < 5; ++kw) {
            float4 wa = *(const float4*)(w0 + (kh * 5 + kw) * 16);
            float4 wb = *(const float4*)(w1r + (kh * 5 + kw) * 16);
            #pragma unroll
            for (int j = 0; j < 2; ++j)
                #pragma unroll
                for (int i = 0; i < 2; ++i) {
                    float va = PV(PA, kh + j, kw + i);
                    float vb = PV(PB, kh + j, kw + i);
                    acc0[0][j][i] = fmaf(va, wa.x, acc0[0][j][i]);
                    acc0[1][j][i] = fmaf(va, wa.y, acc0[1][j][i]);
                    acc0[2][j][i] = fmaf(va, wa.z, acc0[2][j][i]);
                    acc0[3][j][i] = fmaf(va, wa.w, acc0[3][j][i]);
                    acc1[0][j][i] = fmaf(vb, wb.x, acc1[0][j][i]);
                    acc1[1][j][i] = fmaf(vb, wb.y, acc1[1][j][i]);
                    acc1[2][j][i] = fmaf(vb, wb.z, acc1[2][j][i]);
                    acc1[3][j][i] = fmaf(vb, wb.w, acc1[3][j][i]);
                }
        }
    float sc0 = inv[b * 2 + 0], sc1 = inv[b * 2 + 1];
    float4 bias4 = *(const float4*)(cb + ocg * 4);
    float bv[4] = {bias4.x, bias4.y, bias4.z, bias4.w};
    #pragma unroll
    for (int o = 0; o < 4; ++o) {
        float v00 = fmaf(sc1, acc1[o][0][0], sc0 * acc0[o][0][0]);
        float v01 = fmaf(sc1, acc1[o][0][1], sc0 * acc0[o][0][1]);
        float v10 = fmaf(sc1, acc1[o][1][0], sc0 * acc0[o][1][0]);
        float v11 = fmaf(sc1, acc1[o][1][1], sc0 * acc0[o][1][1]);
        float m = fmaxf(fmaxf(v00, v01), fmaxf(v10, v11));
        pool1p[((size_t)(b * 16 + ocg * 4 + o) * 54 + oh + 2) * 56 + ow + 2] =
            fmaxf(m + bv[o], 0.f);
    }
}

// ---------------- Kernel D: conv2 via MFMA implicit GEMM ----------------
__global__ __launch_bounds__(128) void k_conv2(const float* __restrict__ pool1p,
    const unsigned int* __restrict__ wg, const float* __restrict__ cb2,
    float* __restrict__ pool2)
{
    int g = blockIdx.x;
    int b = (g & 7) * 4 + ((g >> 3) & 3);
    int py = g >> 5;
    int t = threadIdx.x;

    __shared__ unsigned short inb[5376];  // [16 ic][6 rows][56 cols] bf16
    {
        const float* src = pool1p + (size_t)b * 48384 + (2 * py) * 56;
        unsigned int* inb32 = (unsigned int*)inb;
        for (int i = t; i < 1344; i += 128) {
            int ic = i / 84, rem = i % 84;
            int r = rem / 14, c4 = rem % 14;
            float4 v = *(const float4*)(src + ic * 3024 + r * 56 + c4 * 4);
            inb32[i * 2 + 0] = pk2(v.x, v.y);
            inb32[i * 2 + 1] = pk2(v.z, v.w);
        }
    }
    __syncthreads();

    int lane = t & 63;
    int h = t >> 6;
    int hh = lane >> 5;
    int sm = lane & 31;
    int cb = h * 32 + sm; if (cb > 49) cb = 49;
    int cbA = cb, cbB = cb + 56;
    int oc = sm;
    int wbase = hh * 128 + oc;

    f32x16 accA = {0.f,0.f,0.f,0.f,0.f,0.f,0.f,0.f,0.f,0.f,0.f,0.f,0.f,0.f,0.f,0.f};
    f32x16 accB = {0.f,0.f,0.f,0.f,0.f,0.f,0.f,0.f,0.f,0.f,0.f,0.f,0.f,0.f,0.f,0.f};

    #pragma unroll
    for (int s = 0; s < 25; ++s) {
        union { short8 v; unsigned int u[4]; } bw;
        bw.u[0] = wg[wbase + s * 256 + 0];
        bw.u[1] = wg[wbase + s * 256 + 32];
        bw.u[2] = wg[wbase + s * 256 + 64];
        bw.u[3] = wg[wbase + s * 256 + 96];
        unsigned short ua[8], ub[8];
        #pragma unroll
        for (int e = 0; e < 8; ++e) {
            int o = hh ? COFF(16 * s + 8 + e) : COFF(16 * s + e);
            ua[e] = inb[cbA + o];
            ub[e] = inb[cbB + o];
        }
        union { short8 v; unsigned int u[4]; } aA, aB;
        #pragma unroll
        for (int r = 0; r < 4; ++r) {
            aA.u[r] = (unsigned int)ua[2 * r] | ((unsigned int)ua[2 * r + 1] << 16);
            aB.u[r] = (unsigned int)ub[2 * r] | ((unsigned int)ub[2 * r + 1] << 16);
        }
        accA = __builtin_amdgcn_mfma_f32_32x32x16_bf16(aA.v, bw.v, accA, 0, 0, 0);
        accB = __builtin_amdgcn_mfma_f32_32x32x16_bf16(aB.v, bw.v, accB, 0, 0, 0);
    }

    float bias = cb2[oc];
    float* dst = pool2 + ((size_t)(b * 32 + oc) * 25 + py) * 25;
    #pragma unroll
    for (int q = 0; q < 4; ++q) {
        float m0 = fmaxf(fmaxf(accA[4 * q + 0], accB[4 * q + 0]),
                         fmaxf(accA[4 * q + 1], accB[4 * q + 1]));
        float m1 = fmaxf(fmaxf(accA[4 * q + 2], accB[4 * q + 2]),
                         fmaxf(accA[4 * q + 3], accB[4 * q + 3]));
        int px0 = h * 16 + 4 * q + 2 * hh;
        if (px0 < 25) dst[px0] = fmaxf(m0 + bias, 0.f);
        if (px0 + 1 < 25) dst[px0 + 1] = fmaxf(m1 + bias, 0.f);
    }
}

// ---------------- Kernel E: final linear (float4) ----------------
__global__ __launch_bounds__(256) void k_fc(const float* __restrict__ pool2,
    const float* __restrict__ oww, const float* __restrict__ ob,
    float* __restrict__ yhat)
{
    int cls = blockIdx.x / BATCH, b = blockIdx.x % BATCH;
    int t = threadIdx.x;
    const float4* y = (const float4*)(pool2 + (size_t)b * 20000);
    const float4* w = (const float4*)(oww + (size_t)cls * 20000);
    float acc = 0.f;
    for (int k = t; k < 5000; k += 256) {
        float4 a = y[k], ww = w[k];
        acc += a.x * ww.x + a.y * ww.y + a.z * ww.z + a.w * ww.w;
    }
    #pragma unroll
    for (int off = 32; off > 0; off >>= 1)
        acc += __shfl_xor(acc, off, 64);
    __shared__ float part[4];
    if ((t & 63) == 0) part[t >> 6] = acc;
    __syncthreads();
    if (t == 0)
        yhat[b * NCLS + cls] = part[0] + part[1] + part[2] + part[3] + ob[cls];
}

extern "C" void kernel_launch(void* const* d_in, const int* in_sizes, int n_in,
                              void* d_out, int out_size, void* d_ws, size_t ws_size,
                              hipStream_t stream)
{
    const float* x   = (const float*)d_in[0];
    const int*   pi0 = (const int*)d_in[1];
    const int*   pi1 = (const int*)d_in[2];
    const float* w1  = (const float*)d_in[3];
    const float* b1  = (const float*)d_in[4];
    const float* w2  = (const float*)d_in[5];
    const float* b2  = (const float*)d_in[6];
    const float* c1w = (const float*)d_in[7];
    const float* c1b = (const float*)d_in[8];
    const float* c2w = (const float*)d_in[9];
    const float* c2b = (const float*)d_in[10];
    const float* oww = (const float*)d_in[11];
    const float* owb = (const float*)d_in[12];
    float* out = (float*)d_out;
    float* ws = (float*)d_ws;

    float*        nf     = ws + NF_OFF;
    float*        wT1    = ws + WT1_OFF;
    unsigned int* wT2b   = (unsigned int*)(ws + WT2B_OFF);
    float*        inv    = ws + INV_OFF;
    unsigned int* cnt    = (unsigned int*)(ws + CNT_OFF);
    float*        imgs_p = ws + IMGSP_OFF;
    float*        pool1p = ws + POOL1P_OFF;
    float*        pool2  = ws + POOL2_OFF;

    k_initfilt<<<NFILT_BLK + 2 + NZBLK, 256, 0, stream>>>(
        x, w1, b1, w2, b2, nf, out + BATCH * NCLS,
        c1w, c2w, wT1, wT2b, ws + CNT_OFF);
    k_pimg <<<256, 256, 0, stream>>>(nf, pi0, pi1, imgs_p, cnt, inv);
    k_conv1<<<1280, 256, 0, stream>>>(imgs_p, wT1, c1b, inv, pool1p);
    k_conv2<<<800, 128, 0, stream>>>(pool1p, wT2b, c2b, pool2);
    k_fc   <<<BATCH * NCLS, 256, 0, stream>>>(pool2, oww, owb, out);
}

// Round 13
// 65.822 us; speedup vs baseline: 1.4852x; 1.4852x over previous
//
#include <hip/hip_runtime.h>
#include <hip/hip_bf16.h>

#define N_NODES 16000
#define IN_F 128
#define HID 64
#define BATCH 32
#define NPAIR 128
#define DRES 100
#define NCLS 10

// workspace layout (float offsets)
#define NF_OFF     0
#define WT1_OFF    16000                 // [2 ic][25 tap][16 oc] fp32 (800)
#define WT2B_OFF   16800                 // [200 kp][32 oc] packed bf16 pairs (6400 uint)
#define INV_OFF    23200                 // (unused, kept for layout)
#define MAXB_OFF   23264                 // [64] per-img max bits (zeroed)
#define IMGSP_OFF  23328                 // [32][2][104][104] padded
#define POOL1P_OFF 715552                // [32][16][54][56] padded
#define POOL2_OFF  2263840               // [32][32][25][25]
#define ZERO_N4    560144                // (64 maxb + imgs + pool1p)/4 float4s, base MAXB_OFF

#define NFILT_BLK  125                   // filt blocks (4 waves x 32 nodes = 128 nodes)
#define NZBLK      548                   // zero blocks (1024 float4 each)

// float2 patch element access (compile-time index under full unroll)
#define PV(P, r, c) (((c) & 1) ? P[(r)*3 + ((c)>>1)].y : P[(r)*3 + ((c)>>1)].x)

typedef short short8 __attribute__((ext_vector_type(8)));
typedef float f32x16 __attribute__((ext_vector_type(16)));

static __device__ __forceinline__ unsigned short f2b(float f) {
    __hip_bfloat16 h = __float2bfloat16(f);
    return *reinterpret_cast<unsigned short*>(&h);
}
static __device__ __forceinline__ unsigned int pk2(float a, float b) {
    return (unsigned int)f2b(a) | ((unsigned int)f2b(b) << 16);
}

// element offset of k=(ic,kh,kw) within inb[16][6][56] (tile row-base 0)
#define COFF(k) (((k)/25)*336 + (((k)%25)/5)*56 + ((k)%25)%5)

// ---------------- Kernel IF: filt MLP (MFMA) + weight prep + zero ----------------
__global__ __launch_bounds__(256) void k_initfilt(
    const float* __restrict__ x, const float* __restrict__ w1,
    const float* __restrict__ b1, const float* __restrict__ w2,
    const float* __restrict__ b2, float* __restrict__ nf, float* __restrict__ out_nf,
    const float* __restrict__ c1w, const float* __restrict__ c2w,
    float* __restrict__ wT1, unsigned int* __restrict__ wT2b,
    float* __restrict__ zbase)
{
    int bx = blockIdx.x, t = threadIdx.x;
    if (bx < NFILT_BLK) {
        int wave = t >> 6, lane = t & 63;
        int n0 = (bx * 4 + wave) * 32;
        int hh = lane >> 5, sm = lane & 31;
        const float* xr = x + (size_t)(n0 + sm) * IN_F + hh * 8;
        const float* wbase = w1 + hh * 512 + sm;

        f32x16 acc0 = {0.f,0.f,0.f,0.f,0.f,0.f,0.f,0.f,0.f,0.f,0.f,0.f,0.f,0.f,0.f,0.f};
        f32x16 acc1 = {0.f,0.f,0.f,0.f,0.f,0.f,0.f,0.f,0.f,0.f,0.f,0.f,0.f,0.f,0.f,0.f};

        #pragma unroll
        for (int s = 0; s < 8; ++s) {
            float4 v0 = *(const float4*)(xr + s * 16);
            float4 v1 = *(const float4*)(xr + s * 16 + 4);
            union { short8 v; unsigned int u[4]; } a;
            a.u[0] = pk2(v0.x, v0.y);
            a.u[1] = pk2(v0.z, v0.w);
            a.u[2] = pk2(v1.x, v1.y);
            a.u[3] = pk2(v1.z, v1.w);
            union { short8 v; unsigned int u[4]; } b0f, b1f;
            #pragma unroll
            for (int r = 0; r < 4; ++r) {
                float wa0 = wbase[s * 1024 + r * 128];
                float wb0 = wbase[s * 1024 + r * 128 + 64];
                float wa1 = wbase[s * 1024 + r * 128 + 32];
                float wb1v = wbase[s * 1024 + r * 128 + 96];
                b0f.u[r] = pk2(wa0, wb0);
                b1f.u[r] = pk2(wa1, wb1v);
            }
            acc0 = __builtin_amdgcn_mfma_f32_32x32x16_bf16(a.v, b0f.v, acc0, 0, 0, 0);
            acc1 = __builtin_amdgcn_mfma_f32_32x32x16_bf16(a.v, b1f.v, acc1, 0, 0, 0);
        }

        int h0 = sm, h1 = 32 + sm;
        float b10 = b1[h0], b11 = b1[h1], w20 = w2[h0], w21 = w2[h1];
        float q[16];
        #pragma unroll
        for (int r = 0; r < 16; ++r)
            q[r] = fmaxf(acc0[r] + b10, 0.f) * w20 + fmaxf(acc1[r] + b11, 0.f) * w21;
        #pragma unroll
        for (int off = 1; off < 32; off <<= 1) {
            #pragma unroll
            for (int r = 0; r < 16; ++r)
                q[r] += __shfl_xor(q[r], off, 64);
        }
        if (sm == 0) {
            float b2v = b2[0];
            #pragma unroll
            for (int r = 0; r < 16; ++r) {
                int m = (r & 3) + 8 * (r >> 2) + 4 * hh;
                float f = 1.f / (1.f + expf(-(q[r] + b2v)));
                nf[n0 + m] = f;
                out_nf[n0 + m] = f;
            }
        }
        return;
    }
    if (bx == NFILT_BLK) {
        for (int i = t; i < 800; i += 256) {
            int ic = i / 400, tap = (i / 16) % 25, oc = i % 16;
            wT1[i] = c1w[(oc * 2 + ic) * 25 + tap];
        }
        return;
    }
    if (bx == NFILT_BLK + 1) {
        for (int i = t; i < 6400; i += 256) {
            int kp = i >> 5, oc = i & 31;
            int k0 = 2 * kp, k1 = k0 + 1;
            float f0 = c2w[(oc * 16 + k0 / 25) * 25 + k0 % 25];
            float f1 = c2w[(oc * 16 + k1 / 25) * 25 + k1 % 25];
            wT2b[i] = pk2(f0, f1);
        }
        return;
    }
    int zi = (bx - (NFILT_BLK + 2)) * 1024 + t;
    float4 z = make_float4(0.f, 0.f, 0.f, 0.f);
    #pragma unroll
    for (int r = 0; r < 4; ++r) {
        int i = zi + r * 256;
        if (i < ZERO_N4) ((float4*)zbase)[i] = z;
    }
}

// ---------------- Kernel B: persistence image, cell-partitioned (no atomicAdd) ----------------
// 256 blocks = (img, col-quarter). Each block: ALL 128 pairs, 25-col slice.
// Thread t<169: (ti,tj); owns cells i=ti+13r (r<8), j=q*25+tj+13s (s<2).
// Each cell written once -> plain stores. Per-img max via one atomicMax/block.
__global__ __launch_bounds__(256) void k_pimg(const float* __restrict__ nf,
    const int* __restrict__ pi0, const int* __restrict__ pi1,
    float* __restrict__ imgs_p, unsigned int* __restrict__ maxb)
{
    int g = blockIdx.x;
    int img = (g & 7) * 8 + ((g >> 3) & 7);
    int q = g >> 6;                 // col quarter
    int b = img >> 1, c = img & 1;
    const int* pi = c ? pi1 : pi0;
    __shared__ float sb[NPAIR], sp[NPAIR];
    __shared__ float wm[4];
    int t = threadIdx.x;
    if (t < NPAIR) {
        int i0 = pi[(b * NPAIR + t) * 2 + 0];
        int i1 = pi[(b * NPAIR + t) * 2 + 1];
        float f0 = nf[i0], f1 = nf[i1];
        sb[t] = f0;
        sp[t] = f1 - f0;
    }
    __syncthreads();
    bool act = t < 169;
    int ti = t / 13, tj = t % 13;
    float acc[8][2] = {};
    if (act) {
        float ci[8];
        #pragma unroll
        for (int r = 0; r < 8; ++r) ci[r] = (float)(ti + 13 * r) * 0.01f;
        float cj0 = (float)(q * 25 + tj) * 0.01f;
        float cj1 = (float)(q * 25 + tj + 13) * 0.01f;
        for (int p = 0; p < NPAIR; ++p) {
            float bb = sb[p], pp = sp[p];
            float d0 = pp - cj0, d1 = pp - cj1;
            float e0 = __expf(-d0 * d0), e1 = __expf(-d1 * d1);
            #pragma unroll
            for (int r = 0; r < 8; ++r) {
                float d = bb - ci[r];
                float eb = __expf(-d * d);
                acc[r][0] = fmaf(eb, e0, acc[r][0]);
                acc[r][1] = fmaf(eb, e1, acc[r][1]);
            }
        }
    }
    float lmax = 0.f;
    if (act) {
        float* dst = imgs_p + (size_t)img * 10816 + 2 * 104 + 2 + q * 25;
        #pragma unroll
        for (int r = 0; r < 8; ++r) {
            int i = ti + 13 * r;
            if (i < DRES) {
                dst[i * 104 + tj] = acc[r][0];
                lmax = fmaxf(lmax, acc[r][0]);
                if (tj < 12) {
                    dst[i * 104 + tj + 13] = acc[r][1];
                    lmax = fmaxf(lmax, acc[r][1]);
                }
            }
        }
    }
    #pragma unroll
    for (int off = 32; off > 0; off >>= 1)
        lmax = fmaxf(lmax, __shfl_xor(lmax, off, 64));
    if ((t & 63) == 0) wm[t >> 6] = lmax;
    __syncthreads();
    if (t == 0) {
        float bm = fmaxf(fmaxf(wm[0], wm[1]), fmaxf(wm[2], wm[3]));
        atomicMax(&maxb[img], __float_as_uint(bm));  // positive floats: uint order ok
    }
}

// ---------------- Kernel C: conv1 + relu + maxpool2 (VALU) ----------------
__global__ __launch_bounds__(256) void k_conv1(const float* __restrict__ imgs_p,
    const float* __restrict__ wT1, const float* __restrict__ cb,
    const unsigned int* __restrict__ maxb, float* __restrict__ pool1p)
{
    int g = blockIdx.x;
    int b = (g & 7) * 4 + ((g >> 3) & 3);
    int ocg = (g >> 5) & 3;
    int rg = g >> 7;
    int t = threadIdx.x;
    if (t >= 250) return;
    int ow = t % 50, oh = rg * 5 + t / 50;

    float2 PA[18], PB[18];
    {
        const float* bs = imgs_p + (size_t)(b * 2 + 0) * 10816 + (2 * oh) * 104 + 2 * ow;
        #pragma unroll
        for (int r = 0; r < 6; ++r) {
            const float* rp = bs + r * 104;
            PA[r * 3 + 0] = *(const float2*)rp;
            PA[r * 3 + 1] = *(const float2*)(rp + 2);
            PA[r * 3 + 2] = *(const float2*)(rp + 4);
        }
        const float* bs1 = bs + 10816;
        #pragma unroll
        for (int r = 0; r < 6; ++r) {
            const float* rp = bs1 + r * 104;
            PB[r * 3 + 0] = *(const float2*)rp;
            PB[r * 3 + 1] = *(const float2*)(rp + 2);
            PB[r * 3 + 2] = *(const float2*)(rp + 4);
        }
    }
    float acc0[4][2][2] = {}, acc1[4][2][2] = {};
    const float* w0 = wT1 + ocg * 4;
    const float* w1r = wT1 + 400 + ocg * 4;
    #pragma unroll
    for (int kh = 0; kh < 5; ++kh)
        #pragma unroll
        for (int kw = 0; kw < 5; ++kw) {
            float4 wa = *(const float4*)(w0 + (kh * 5 + kw) * 16);
            float4 wb = *(const float4*)(w1r + (kh * 5 + kw) * 16);
            #pragma unroll
            for (int j = 0; j < 2; ++j)
                #pragma unroll
                for (int i = 0; i < 2; ++i) {
                    float va = PV(PA, kh + j, kw + i);
                    float vb = PV(PB, kh + j, kw + i);
                    acc0[0][j][i] = fmaf(va, wa.x, acc0[0][j][i]);
                    acc0[1][j][i] = fmaf(va, wa.y, acc0[1][j][i]);
                    acc0[2][j][i] = fmaf(va, wa.z, acc0[2][j][i]);
                    acc0[3][j][i] = fmaf(va, wa.w, acc0[3][j][i]);
                    acc1[0][j][i] = fmaf(vb, wb.x, acc1[0][j][i]);
                    acc1[1][j][i] = fmaf(vb, wb.y, acc1[1][j][i]);
                    acc1[2][j][i] = fmaf(vb, wb.z, acc1[2][j][i]);
                    acc1[3][j][i] = fmaf(vb, wb.w, acc1[3][j][i]);
                }
        }
    float sc0 = 1.f / __uint_as_float(maxb[b * 2 + 0]);
    float sc1 = 1.f / __uint_as_float(maxb[b * 2 + 1]);
    float4 bias4 = *(const float4*)(cb + ocg * 4);
    float bv[4] = {bias4.x, bias4.y, bias4.z, bias4.w};
    #pragma unroll
    for (int o = 0; o < 4; ++o) {
        float v00 = fmaf(sc1, acc1[o][0][0], sc0 * acc0[o][0][0]);
        float v01 = fmaf(sc1, acc1[o][0][1], sc0 * acc0[o][0][1]);
        float v10 = fmaf(sc1, acc1[o][1][0], sc0 * acc0[o][1][0]);
        float v11 = fmaf(sc1, acc1[o][1][1], sc0 * acc0[o][1][1]);
        float m = fmaxf(fmaxf(v00, v01), fmaxf(v10, v11));
        pool1p[((size_t)(b * 16 + ocg * 4 + o) * 54 + oh + 2) * 56 + ow + 2] =
            fmaxf(m + bv[o], 0.f);
    }
}

// ---------------- Kernel D: conv2 via MFMA implicit GEMM ----------------
__global__ __launch_bounds__(128) void k_conv2(const float* __restrict__ pool1p,
    const unsigned int* __restrict__ wg, const float* __restrict__ cb2,
    float* __restrict__ pool2)
{
    int g = blockIdx.x;
    int b = (g & 7) * 4 + ((g >> 3) & 3);
    int py = g >> 5;
    int t = threadIdx.x;

    __shared__ unsigned short inb[5376];  // [16 ic][6 rows][56 cols] bf16
    {
        const float* src = pool1p + (size_t)b * 48384 + (2 * py) * 56;
        unsigned int* inb32 = (unsigned int*)inb;
        for (int i = t; i < 1344; i += 128) {
            int ic = i / 84, rem = i % 84;
            int r = rem / 14, c4 = rem % 14;
            float4 v = *(const float4*)(src + ic * 3024 + r * 56 + c4 * 4);
            inb32[i * 2 + 0] = pk2(v.x, v.y);
            inb32[i * 2 + 1] = pk2(v.z, v.w);
        }
    }
    __syncthreads();

    int lane = t & 63;
    int h = t >> 6;
    int hh = lane >> 5;
    int sm = lane & 31;
    int cb = h * 32 + sm; if (cb > 49) cb = 49;
    int cbA = cb, cbB = cb + 56;
    int oc = sm;
    int wbase = hh * 128 + oc;

    f32x16 accA = {0.f,0.f,0.f,0.f,0.f,0.f,0.f,0.f,0.f,0.f,0.f,0.f,0.f,0.f,0.f,0.f};
    f32x16 accB = {0.f,0.f,0.f,0.f,0.f,0.f,0.f,0.f,0.f,0.f,0.f,0.f,0.f,0.f,0.f,0.f};

    #pragma unroll
    for (int s = 0; s < 25; ++s) {
        union { short8 v; unsigned int u[4]; } bw;
        bw.u[0] = wg[wbase + s * 256 + 0];
        bw.u[1] = wg[wbase + s * 256 + 32];
        bw.u[2] = wg[wbase + s * 256 + 64];
        bw.u[3] = wg[wbase + s * 256 + 96];
        unsigned short ua[8], ub[8];
        #pragma unroll
        for (int e = 0; e < 8; ++e) {
            int o = hh ? COFF(16 * s + 8 + e) : COFF(16 * s + e);
            ua[e] = inb[cbA + o];
            ub[e] = inb[cbB + o];
        }
        union { short8 v; unsigned int u[4]; } aA, aB;
        #pragma unroll
        for (int r = 0; r < 4; ++r) {
            aA.u[r] = (unsigned int)ua[2 * r] | ((unsigned int)ua[2 * r + 1] << 16);
            aB.u[r] = (unsigned int)ub[2 * r] | ((unsigned int)ub[2 * r + 1] << 16);
        }
        accA = __builtin_amdgcn_mfma_f32_32x32x16_bf16(aA.v, bw.v, accA, 0, 0, 0);
        accB = __builtin_amdgcn_mfma_f32_32x32x16_bf16(aB.v, bw.v, accB, 0, 0, 0);
    }

    float bias = cb2[oc];
    float* dst = pool2 + ((size_t)(b * 32 + oc) * 25 + py) * 25;
    #pragma unroll
    for (int q = 0; q < 4; ++q) {
        float m0 = fmaxf(fmaxf(accA[4 * q + 0], accB[4 * q + 0]),
                         fmaxf(accA[4 * q + 1], accB[4 * q + 1]));
        float m1 = fmaxf(fmaxf(accA[4 * q + 2], accB[4 * q + 2]),
                         fmaxf(accA[4 * q + 3], accB[4 * q + 3]));
        int px0 = h * 16 + 4 * q + 2 * hh;
        if (px0 < 25) dst[px0] = fmaxf(m0 + bias, 0.f);
        if (px0 + 1 < 25) dst[px0 + 1] = fmaxf(m1 + bias, 0.f);
    }
}

// ---------------- Kernel E: final linear (float4) ----------------
__global__ __launch_bounds__(256) void k_fc(const float* __restrict__ pool2,
    const float* __restrict__ oww, const float* __restrict__ ob,
    float* __restrict__ yhat)
{
    int cls = blockIdx.x / BATCH, b = blockIdx.x % BATCH;
    int t = threadIdx.x;
    const float4* y = (const float4*)(pool2 + (size_t)b * 20000);
    const float4* w = (const float4*)(oww + (size_t)cls * 20000);
    float acc = 0.f;
    for (int k = t; k < 5000; k += 256) {
        float4 a = y[k], ww = w[k];
        acc += a.x * ww.x + a.y * ww.y + a.z * ww.z + a.w * ww.w;
    }
    #pragma unroll
    for (int off = 32; off > 0; off >>= 1)
        acc += __shfl_xor(acc, off, 64);
    __shared__ float part[4];
    if ((t & 63) == 0) part[t >> 6] = acc;
    __syncthreads();
    if (t == 0)
        yhat[b * NCLS + cls] = part[0] + part[1] + part[2] + part[3] + ob[cls];
}

extern "C" void kernel_launch(void* const* d_in, const int* in_sizes, int n_in,
                              void* d_out, int out_size, void* d_ws, size_t ws_size,
                              hipStream_t stream)
{
    const float* x   = (const float*)d_in[0];
    const int*   pi0 = (const int*)d_in[1];
    const int*   pi1 = (const int*)d_in[2];
    const float* w1  = (const float*)d_in[3];
    const float* b1  = (const float*)d_in[4];
    const float* w2  = (const float*)d_in[5];
    const float* b2  = (const float*)d_in[6];
    const float* c1w = (const float*)d_in[7];
    const float* c1b = (const float*)d_in[8];
    const float* c2w = (const float*)d_in[9];
    const float* c2b = (const float*)d_in[10];
    const float* oww = (const float*)d_in[11];
    const float* owb = (const float*)d_in[12];
    float* out = (float*)d_out;
    float* ws = (float*)d_ws;

    float*        nf     = ws + NF_OFF;
    float*        wT1    = ws + WT1_OFF;
    unsigned int* wT2b   = (unsigned int*)(ws + WT2B_OFF);
    unsigned int* maxb   = (unsigned int*)(ws + MAXB_OFF);
    float*        imgs_p = ws + IMGSP_OFF;
    float*        pool1p = ws + POOL1P_OFF;
    float*        pool2  = ws + POOL2_OFF;

    k_initfilt<<<NFILT_BLK + 2 + NZBLK, 256, 0, stream>>>(
        x, w1, b1, w2, b2, nf, out + BATCH * NCLS,
        c1w, c2w, wT1, wT2b, ws + MAXB_OFF);
    k_pimg <<<256, 256, 0, stream>>>(nf, pi0, pi1, imgs_p, maxb);
    k_conv1<<<1280, 256, 0, stream>>>(imgs_p, wT1, c1b, maxb, pool1p);
    k_conv2<<<800, 128, 0, stream>>>(pool1p, wT2b, c2b, pool2);
    k_fc   <<<BATCH * NCLS, 256, 0, stream>>>(pool2, oww, owb, out);
}